// Round 1
// baseline (919.323 us; speedup 1.0000x reference)
//
#include <hip/hip_runtime.h>
#include <cstdint>
#include <cstddef>

#define B_ 2
#define L_ 2048
#define V_ 32001
#define MASKTOK (V_ - 1)
#define EPS_  1e-3f
#define GEPS_ 1e-6f
#define NTHREADS 256

__global__ __launch_bounds__(NTHREADS) void euler_kernel(
    const float* __restrict__ output,   // [B,L,V]
    const int*   __restrict__ xt,       // [B,L]
    const float* __restrict__ t,        // [B]
    const float* __restrict__ step_p,   // [1]
    const float* __restrict__ u,        // [B,L,V]
    float* __restrict__ out_xnew,       // [B*L]  (x_new as float)
    float* __restrict__ out_rev)        // [B*L*V]
{
    const int row = blockIdx.x;         // 0 .. B*L-1
    const int tid = threadIdx.x;
    const int b   = row / L_;

    int x = xt[row];
    if (x == -1) x = MASKTOK;

    float* __restrict__ rev = out_rev + (size_t)row * V_;

    // ---- Fast path: xt is not the mask token -> rev_rate == 0, x_new == xt ----
    if (x != MASKTOK) {
        if (tid == 0) out_xnew[row] = (float)x;
        // alignment-peeled float4 zero fill (rows shift phase by 4B each: V=32001)
        uintptr_t p = (uintptr_t)rev;
        int head = (int)(((16u - (unsigned)(p & 15u)) & 15u) >> 2);  // 0..3 floats
        if (head > V_) head = V_;
        for (int i = tid; i < head; i += NTHREADS) rev[i] = 0.0f;
        const int n4 = (V_ - head) >> 2;
        float4* __restrict__ r4 = (float4*)(rev + head);
        const float4 z = make_float4(0.f, 0.f, 0.f, 0.f);
        for (int i = tid; i < n4; i += NTHREADS) r4[i] = z;
        const int done = head + (n4 << 2);
        for (int i = done + tid; i < V_; i += NTHREADS) rev[i] = 0.0f;
        return;
    }

    // ---- Mask row: full compute, single pass over output/u ----
    const float step  = step_p[0];
    const float om    = 1.0f - EPS_;            // 0.999
    const float sigma = om / (1.0f - om * t[b]);

    const float* __restrict__ orow = output + (size_t)row * V_;
    const float* __restrict__ urow = u      + (size_t)row * V_;

    float lsum  = 0.0f;
    float bestv = -3.4e38f;
    int   besti = 0;

    auto proc = [&](int v, float ov, float uv) {
        float sc = expf(ov);
        float rr = sigma * sc;
        rev[v] = rr;
        lsum += sc;
        float g   = GEPS_ - logf(GEPS_ + (1.0f - GEPS_) * uv);
        float val = (step * rr) / g;            // xt_prob[v] = 0 + step*rr
        if (val > bestv) { bestv = val; besti = v; }
    };

    const int n = V_ - 1;                       // exclude the mask (last) entry
    uintptr_t p = (uintptr_t)rev;               // orow/urow/rev share byte phase
    int head = (int)(((16u - (unsigned)(p & 15u)) & 15u) >> 2);
    if (head > n) head = n;
    for (int v = tid; v < head; v += NTHREADS) proc(v, orow[v], urow[v]);

    const int n4 = (n - head) >> 2;
    const float4* __restrict__ o4 = (const float4*)(orow + head);
    const float4* __restrict__ u4 = (const float4*)(urow + head);
    for (int i = tid; i < n4; i += NTHREADS) {
        float4 ov = o4[i];
        float4 uv = u4[i];
        int base = head + (i << 2);
        proc(base + 0, ov.x, uv.x);
        proc(base + 1, ov.y, uv.y);
        proc(base + 2, ov.z, uv.z);
        proc(base + 3, ov.w, uv.w);
    }
    const int done = head + (n4 << 2);
    for (int v = done + tid; v < n; v += NTHREADS) proc(v, orow[v], urow[v]);

    // ---- block reduction: sum + argmax (ties -> lower index, numpy semantics) ----
    __shared__ float s_sum[NTHREADS];
    __shared__ float s_val[NTHREADS];
    __shared__ int   s_idx[NTHREADS];
    s_sum[tid] = lsum; s_val[tid] = bestv; s_idx[tid] = besti;
    __syncthreads();
    for (int off = NTHREADS / 2; off > 0; off >>= 1) {
        if (tid < off) {
            s_sum[tid] += s_sum[tid + off];
            float v2 = s_val[tid + off];
            int   i2 = s_idx[tid + off];
            if (v2 > s_val[tid] || (v2 == s_val[tid] && i2 < s_idx[tid])) {
                s_val[tid] = v2; s_idx[tid] = i2;
            }
        }
        __syncthreads();
    }

    if (tid == 0) {
        float sum  = s_sum[0];
        float rr_m = sigma * (-sum);            // rev_rate at the mask entry
        rev[MASKTOK] = rr_m;
        float g_m = GEPS_ - logf(GEPS_ + (1.0f - GEPS_) * urow[MASKTOK]);
        float v_m = (1.0f + step * rr_m) / g_m; // xt_prob[mask] = 1 + step*rr_m
        int   idx = s_idx[0];
        // mask entry is the LAST index: wins only if strictly greater
        if (v_m > s_val[0]) idx = MASKTOK;
        out_xnew[row] = (idx == MASKTOK) ? -1.0f : (float)idx;
    }
}

extern "C" void kernel_launch(void* const* d_in, const int* in_sizes, int n_in,
                              void* d_out, int out_size, void* d_ws, size_t ws_size,
                              hipStream_t stream) {
    const float* output = (const float*)d_in[0];
    const int*   xt     = (const int*)  d_in[1];
    const float* t      = (const float*)d_in[2];
    const float* step   = (const float*)d_in[3];
    const float* u      = (const float*)d_in[4];

    float* out_xnew = (float*)d_out;             // first B*L elements
    float* out_rev  = out_xnew + (size_t)B_ * L_;

    euler_kernel<<<dim3(B_ * L_), NTHREADS, 0, stream>>>(
        output, xt, t, step, u, out_xnew, out_rev);
}